// Round 20
// baseline (41.288 us; speedup 1.0000x reference)
//
#include <hip/hip_runtime.h>

#define NT   512    // 8 waves
#define IMG  512
#define BTR  64     // block output tile rows
#define BTC  128    // block output tile cols (8 waves x 16-col strips)
#define RAWR 74     // staged rows: 64+10 halo; rows 74..79 have zero V-weight
#define RAWU 76     // raw row stride in uints (72 data + 4 pad; 76%32=12 -> 2-way max)
#define WS_PARTIAL_OFF 1024   // floats; band table occupies first 4KB of ws

typedef _Float16 f16x8 __attribute__((ext_vector_type(8)));
typedef _Float16 f16x4 __attribute__((ext_vector_type(4)));
typedef float    f32x4 __attribute__((ext_vector_type(4)));

__device__ inline unsigned pk2(float a, float b) {
    auto r = __builtin_amdgcn_cvt_pkrtz(a, b);     // f32x2 -> f16x2 (RTZ)
    return __builtin_bit_cast(unsigned, r);
}

// ---------------------------------------------------------------------------
// One-time init: per-lane band fragments -> ws (kept separate: round 18
// showed in-block rebuild costs ~2 us on the block critical path).
//   tab[l*16+0..3] : B1 frag, K=32 h-conv B operand, B1[k][n]=w[k-n-3]
//   tab[l*16+4..5] : A2 k-tile 0 (K=16 v-conv A), A2[r][k]=w[k-r]
//   tab[l*16+6..7] : A2 k-tile 1,                  w[k+16-r]
// ---------------------------------------------------------------------------
__global__ void ssim_init_kernel(const float* __restrict__ kern,
                                 unsigned* __restrict__ tab) {
    const int l  = threadIdx.x;        // 0..63
    const int lm = l & 15;
    const int lg = l >> 4;
    const float invg = 1.0f / sqrtf(kern[60]);
    auto wof = [&](int i) -> float {
        return ((unsigned)i <= 10u) ? kern[55 + i] * invg : 0.0f;
    };
    unsigned bu[4], au[4];
    #pragma unroll
    for (int jp = 0; jp < 4; ++jp) {
        const int d = 8 * lg + 2 * jp - lm - 3;
        bu[jp] = pk2(wof(d), wof(d + 1));
    }
    #pragma unroll
    for (int jp = 0; jp < 2; ++jp) {
        const int e = 4 * lg + 2 * jp - lm;
        au[jp]     = pk2(wof(e),      wof(e + 1));
        au[2 + jp] = pk2(wof(e + 16), wof(e + 17));
    }
    *(uint4*)&tab[l * 16]     = make_uint4(bu[0], bu[1], bu[2], bu[3]);
    *(uint4*)&tab[l * 16 + 4] = make_uint4(au[0], au[1], au[2], au[3]);
}

// ---------------------------------------------------------------------------
// SSIM via MFMA, v14 = v10 (35.8 us) widened to a 64x128 tile / 512 threads.
// Per-wave work is EXACTLY v10's (16-col strip, 5 rolling H m-tiles, 4
// quadrants) - the verified compute path is untouched. Gains: 2x setup
// amortization, halo overfetch 1.45x -> 1.30x, 2048 blocks. LDS 44 KB ->
// 3 blocks/CU x 8 waves = 24 waves/CU (same residency as v10's 6x4).
// Null/reverted levers: T14 preload (v6), T2 swizzle (v7), atomic fused
// reduce (v11: agent-scope atomics poison XCD L2, 7x), in-block band build
// (v12), T5 setprio (v13: null).
// Compute structure (verified bit-exact rounds 14-19):
//   H-conv:  H[m][16ct+n] = sum_k raw[m][16ct+k] * B1[k][n], B1[k][n]=w[k-n-3]
//   V-conv:  out[16rt+r][n] = sum_j w[j-r] * H[16rt+j][n] (two chained K=16
//            MFMAs; C-layout of K=32 MFMA == B-layout of K=16 MFMA)
//   PP/TT/PT A-frags derived in-register as products of P/T frags.
//   74 staged rows; mt=4 lm>=10 clamps to row 73 (zero V-weight, bit-exact).
// launch_bounds(512,4): VGPR cap 128 >> actual ~44; round 4 showed tighter
// caps spill to scratch.
// ---------------------------------------------------------------------------
__global__ __launch_bounds__(NT, 4) void ssim_mfma_kernel(
    const float* __restrict__ pred,
    const float* __restrict__ target,
    const unsigned* __restrict__ tab,
    float* __restrict__ partial)
{
    __shared__ __align__(16) unsigned sRaw[2][RAWR][RAWU];   // 44 KB
    __shared__ float sRed[8];

    const int tid = threadIdx.x;

    // ---- bijective XCD swizzle (gridDim.x % 8 == 0) ----
    const int bid   = blockIdx.x;
    const int chunk = (int)gridDim.x >> 3;
    const int swz   = (bid & 7) * chunk + (bid >> 3);
    const int img   = swz >> 5;               // 32 tiles per image (8 rows x 4 cols)
    const int rem   = swz & 31;
    const int tx0   = (rem & 3) * BTC;
    const int ty0   = (rem >> 2) * BTR;

    const int lane = tid & 63;
    const int wv   = tid >> 6;      // 0..7 = 16-col strip index
    const int lm   = lane & 15;     // m (A row) / n (B col) / C col
    const int lg   = lane >> 4;     // k-group; C row-group

    // ---- band fragments: two L2-hit vector loads ----
    const uint4 bq = *(const uint4*)&tab[lane * 16];
    const uint4 aq = *(const uint4*)&tab[lane * 16 + 4];
    const f16x8 bfrag = __builtin_bit_cast(f16x8, bq);
    const f16x4 a2k0  = __builtin_bit_cast(f16x4, make_uint2(aq.x, aq.y));
    const f16x4 a2k1  = __builtin_bit_cast(f16x4, make_uint2(aq.z, aq.w));
    const f32x4 zero4 = {0.f, 0.f, 0.f, 0.f};

    // ---- stage raw P,T (f16): 74 rows x 18 groups of 8 px ----
    {
        const float* pimg = pred   + (size_t)img * (IMG * IMG);
        const float* timg = target + (size_t)img * (IMG * IMG);
        if ((unsigned)(tx0 - 128) <= 128u && (unsigned)(ty0 - 64) <= 320u) {
            #pragma unroll
            for (int i = tid; i < RAWR * 18; i += NT) {
                const int r  = i / 18;
                const int cg = i - r * 18;
                const float* prow = pimg + (ty0 - 5 + r) * IMG + (tx0 - 8 + 8 * cg);
                const float* trow = timg + (ty0 - 5 + r) * IMG + (tx0 - 8 + 8 * cg);
                const float4 p0 = *(const float4*)(prow);
                const float4 p1 = *(const float4*)(prow + 4);
                const float4 t0 = *(const float4*)(trow);
                const float4 t1 = *(const float4*)(trow + 4);
                const int u = 4 * cg;
                *(uint4*)&sRaw[0][r][u] = make_uint4(pk2(p0.x, p0.y), pk2(p0.z, p0.w),
                                                     pk2(p1.x, p1.y), pk2(p1.z, p1.w));
                *(uint4*)&sRaw[1][r][u] = make_uint4(pk2(t0.x, t0.y), pk2(t0.z, t0.w),
                                                     pk2(t1.x, t1.y), pk2(t1.z, t1.w));
            }
        } else {
            for (int i = tid; i < RAWR * 18; i += NT) {
                const int r  = i / 18;
                const int cg = i - r * 18;
                const int gy = ty0 - 5 + r;
                const int gx = tx0 - 8 + 8 * cg;     // multiple of 8
                float4 p0 = make_float4(0.f, 0.f, 0.f, 0.f), p1 = p0, t0 = p0, t1 = p0;
                if ((unsigned)gy < IMG) {
                    const float* prow = pimg + gy * IMG;
                    const float* trow = timg + gy * IMG;
                    if ((unsigned)gx < IMG) {
                        p0 = *(const float4*)(prow + gx);
                        t0 = *(const float4*)(trow + gx);
                    }
                    if ((unsigned)(gx + 4) < IMG) {
                        p1 = *(const float4*)(prow + gx + 4);
                        t1 = *(const float4*)(trow + gx + 4);
                    }
                }
                const int u = 4 * cg;
                *(uint4*)&sRaw[0][r][u] = make_uint4(pk2(p0.x, p0.y), pk2(p0.z, p0.w),
                                                     pk2(p1.x, p1.y), pk2(p1.z, p1.w));
                *(uint4*)&sRaw[1][r][u] = make_uint4(pk2(t0.x, t0.y), pk2(t0.z, t0.w),
                                                     pk2(t1.x, t1.y), pk2(t1.z, t1.w));
            }
        }
    }
    __syncthreads();   // the only compute barrier

    // ---- per-wave: col strip ct = wv; rolling H m-tile pipeline ----
    const int co = 8 * wv;        // k-window uint base (raw px 16*wv)

    #define COMPUTE_H(mt, outf)                                                     \
    {                                                                               \
        const int rr = ((mt) == 4 && lm >= 10) ? 73 : 16 * (mt) + lm;               \
        const f16x8 aP = __builtin_bit_cast(f16x8,                                  \
            *(const uint4*)&sRaw[0][rr][co + 4 * lg]);                              \
        const f16x8 aT = __builtin_bit_cast(f16x8,                                  \
            *(const uint4*)&sRaw[1][rr][co + 4 * lg]);                              \
        f16x8 af[5];                                                                \
        af[0] = aP; af[1] = aT;                                                     \
        af[2] = aP * aP;                                                            \
        af[3] = aT * aT;                                                            \
        af[4] = aP * aT;                                                            \
        _Pragma("unroll")                                                           \
        for (int ch = 0; ch < 5; ++ch) {                                            \
            const f32x4 h = __builtin_amdgcn_mfma_f32_16x16x32_f16(af[ch], bfrag,   \
                                                                   zero4, 0, 0, 0); \
            outf[ch] = __builtin_bit_cast(f16x4,                                    \
                make_uint2(pk2(h[0], h[1]), pk2(h[2], h[3])));                      \
        }                                                                           \
    }

    f16x4 bcur[5], bnext[5];
    COMPUTE_H(0, bcur);

    float lsum = 0.f;
    #pragma unroll
    for (int rt = 0; rt < 4; ++rt) {
        COMPUTE_H(rt + 1, bnext);

        f32x4 M[5];
        #pragma unroll
        for (int ch = 0; ch < 5; ++ch) {
            const f32x4 m0 = __builtin_amdgcn_mfma_f32_16x16x16f16(a2k0, bcur[ch], zero4, 0, 0, 0);
            M[ch]          = __builtin_amdgcn_mfma_f32_16x16x16f16(a2k1, bnext[ch], m0,   0, 0, 0);
        }

        #pragma unroll
        for (int r = 0; r < 4; ++r) {
            const float mx = M[0][r], my = M[1][r];
            const float exx = M[2][r], eyy = M[3][r], exy = M[4][r];
            const float mxx = mx * mx, myy = my * my, mxy = mx * my;
            const float sx  = exx - mxx;
            const float sy  = eyy - myy;
            const float sxy = exy - mxy;
            const float num = (2.0f * mxy + 1e-4f) * (2.0f * sxy + 9e-4f);
            const float den = (mxx + myy + 1e-4f) * (sx + sy + 9e-4f);
            lsum = fmaf(num, __builtin_amdgcn_rcpf(den), lsum);
        }

        #pragma unroll
        for (int ch = 0; ch < 5; ++ch) bcur[ch] = bnext[ch];
    }
    #undef COMPUTE_H

    // ---- block reduction -> one partial per block ----
    #pragma unroll
    for (int off = 32; off > 0; off >>= 1)
        lsum += __shfl_down(lsum, off, 64);
    if (lane == 0) sRed[wv] = lsum;
    __syncthreads();
    if (tid == 0) {
        float p = 0.f;
        #pragma unroll
        for (int q = 0; q < 8; ++q) p += sRed[q];
        partial[bid] = p;
    }
}

// ---------------------------------------------------------------------------
// Final reduction: sum partials, out = 1 - mean   (1 block x 1024 threads)
// ---------------------------------------------------------------------------
#define NR 1024
__global__ __launch_bounds__(NR) void ssim_reduce_kernel(
    const float* __restrict__ partial, float* __restrict__ out,
    int n, float inv_npix)
{
    __shared__ float sRed[16];
    float s = 0.0f;
    const int n4 = n >> 2;
    for (int i = threadIdx.x; i < n4; i += NR) {
        const float4 v = ((const float4*)partial)[i];
        s += (v.x + v.y) + (v.z + v.w);
    }
    for (int i = (n4 << 2) + threadIdx.x; i < n; i += NR) s += partial[i];
    #pragma unroll
    for (int off = 32; off > 0; off >>= 1)
        s += __shfl_down(s, off, 64);
    if ((threadIdx.x & 63) == 0) sRed[threadIdx.x >> 6] = s;
    __syncthreads();
    if (threadIdx.x == 0) {
        float tot = 0.0f;
        #pragma unroll
        for (int q = 0; q < 16; ++q) tot += sRed[q];
        out[0] = 1.0f - tot * inv_npix;
    }
}

extern "C" void kernel_launch(void* const* d_in, const int* in_sizes, int n_in,
                              void* d_out, int out_size, void* d_ws, size_t ws_size,
                              hipStream_t stream) {
    const float* pred   = (const float*)d_in[0];
    const float* target = (const float*)d_in[1];
    const float* kern   = (const float*)d_in[2];
    float* out     = (float*)d_out;
    unsigned* tab  = (unsigned*)d_ws;                       // 4 KB band table
    float* partial = (float*)d_ws + WS_PARTIAL_OFF;         // per-block sums

    const int nimg    = in_sizes[0] / (IMG * IMG);          // 64
    const int nblocks = (IMG / BTR) * (IMG / BTC) * nimg;   // 2048 (mult of 8)
    const float inv_npix = 1.0f / ((float)nimg * (float)(IMG * IMG));

    ssim_init_kernel<<<1, 64, 0, stream>>>(kern, tab);
    ssim_mfma_kernel<<<dim3(nblocks), NT, 0, stream>>>(pred, target, tab, partial);
    ssim_reduce_kernel<<<1, NR, 0, stream>>>(partial, out, nblocks, inv_npix);
}

// Round 21
// 40.130 us; speedup vs baseline: 1.0289x; 1.0289x over previous
//
#include <hip/hip_runtime.h>

#define NT   256
#define IMG  512
#define BT   64     // block output tile: 64x64 (4 waves x 4 rt-quadrants)
#define RAWR 74     // staged rows: 64+10 halo; rows 74..79 have zero V-weight
#define RAWU 44     // raw row stride in uints (40 data + 4 pad)

typedef _Float16 f16x8 __attribute__((ext_vector_type(8)));
typedef _Float16 f16x4 __attribute__((ext_vector_type(4)));
typedef float    f32x4 __attribute__((ext_vector_type(4)));

__device__ inline unsigned pk2(float a, float b) {
    auto r = __builtin_amdgcn_cvt_pkrtz(a, b);     // f32x2 -> f16x2 (RTZ)
    return __builtin_bit_cast(unsigned, r);
}

// ---------------------------------------------------------------------------
// Staging helpers (item i -> row r=i/10, col-group cg=i%10, 8 px of P and T).
// ---------------------------------------------------------------------------
__device__ inline void load_item(const float* __restrict__ pimg,
                                 const float* __restrict__ timg,
                                 int ty0, int tx0, bool interior, int i,
                                 float4& p0, float4& p1, float4& t0, float4& t1) {
    const int r  = i / 10;
    const int cg = i - r * 10;
    const int gy = ty0 - 5 + r;
    const int gx = tx0 - 8 + 8 * cg;     // multiple of 4
    if (interior) {
        const float* prow = pimg + gy * IMG + gx;
        const float* trow = timg + gy * IMG + gx;
        p0 = *(const float4*)(prow);
        p1 = *(const float4*)(prow + 4);
        t0 = *(const float4*)(trow);
        t1 = *(const float4*)(trow + 4);
    } else {
        p0 = make_float4(0.f, 0.f, 0.f, 0.f); p1 = p0; t0 = p0; t1 = p0;
        if ((unsigned)gy < IMG) {
            const float* prow = pimg + gy * IMG;
            const float* trow = timg + gy * IMG;
            if ((unsigned)gx < IMG)       { p0 = *(const float4*)(prow + gx);
                                            t0 = *(const float4*)(trow + gx); }
            if ((unsigned)(gx + 4) < IMG) { p1 = *(const float4*)(prow + gx + 4);
                                            t1 = *(const float4*)(trow + gx + 4); }
        }
    }
}

__device__ inline void write_item(unsigned (&sRaw)[2][RAWR][RAWU], int i,
                                  const float4& p0, const float4& p1,
                                  const float4& t0, const float4& t1) {
    const int r  = i / 10;
    const int cg = i - r * 10;
    const int u  = 4 * cg;
    *(uint4*)&sRaw[0][r][u] = make_uint4(pk2(p0.x, p0.y), pk2(p0.z, p0.w),
                                         pk2(p1.x, p1.y), pk2(p1.z, p1.w));
    *(uint4*)&sRaw[1][r][u] = make_uint4(pk2(t0.x, t0.y), pk2(t0.z, t0.w),
                                         pk2(t1.x, t1.y), pk2(t1.z, t1.w));
}

// ---------------------------------------------------------------------------
// SSIM via MFMA, v15 = v10 (35.8 us) with the init kernel fused in, HIDDEN
// under staging-load latency: item-0's 4 global loads issue FIRST, the band
// build (17 L2-hit kern loads + ~90 VALU) runs while they're in flight, then
// pack/write proceeds. Round 18 proved band-before-loads costs ~2 us; this
// ordering makes it ~free and deletes the init dispatch (~2-3 us).
// v14 (64x128/8-wave) REVERTED: occupancy 48->36%, 41.3 us. Also reverted:
// T14 preload (v6), T2 swizzle (v7), atomic fused reduce (v11: agent-scope
// atomics poison XCD L2), setprio (v13: null).
// Compute structure (verified bit-exact rounds 14-19):
//   H-conv:  H[m][16ct+n] = sum_k raw[m][16ct+k] * B1[k][n], B1[k][n]=w[k-n-3]
//   V-conv:  out[16rt+r][n] = sum_j w[j-r] * H[16rt+j][n] (two chained K=16
//            MFMAs; C-layout of K=32 MFMA == B-layout of K=16 MFMA)
//   PP/TT/PT A-frags derived in-register as products of P/T frags.
//   74 staged rows; mt=4 lm>=10 clamps to row 73 (zero V-weight, bit-exact).
// launch_bounds(256,4): round 4 showed tighter caps spill to scratch.
// VGPR watch: must stay <=64 (m69 cliff) or occupancy halves — v10 was 40.
// ---------------------------------------------------------------------------
__global__ __launch_bounds__(NT, 4) void ssim_mfma_kernel(
    const float* __restrict__ pred,
    const float* __restrict__ target,
    const float* __restrict__ kern,
    float* __restrict__ partial)
{
    __shared__ __align__(16) unsigned sRaw[2][RAWR][RAWU];   // 25.4 KB
    __shared__ float sRed[4];

    const int tid = threadIdx.x;

    // ---- bijective XCD swizzle (gridDim.x % 8 == 0) ----
    const int bid   = blockIdx.x;
    const int chunk = (int)gridDim.x >> 3;
    const int swz   = (bid & 7) * chunk + (bid >> 3);
    const int img   = swz >> 6;               // 64 tiles per image
    const int rem   = swz & 63;
    const int tx0   = (rem & 7) * BT;
    const int ty0   = (rem >> 3) * BT;

    const int lane = tid & 63;
    const int wv   = tid >> 6;
    const int lm   = lane & 15;     // m (A row) / n (B col) / C col
    const int lg   = lane >> 4;     // k-group; C row-group

    const float* pimg = pred   + (size_t)img * (IMG * IMG);
    const float* timg = target + (size_t)img * (IMG * IMG);
    const bool interior = (unsigned)(tx0 - 64) <= 320u && (unsigned)(ty0 - 64) <= 320u;

    // ---- item-0 staging loads: issued FIRST (longest latency) ----
    float4 p0a, p1a, t0a, t1a;
    load_item(pimg, timg, ty0, tx0, interior, tid, p0a, p1a, t0a, t1a);

    // ---- band fragments from kern: VALU + L2-hit loads, hidden under the
    //      in-flight item-0 staging loads (identical arithmetic to the old
    //      init kernel -> bit-identical result) ----
    const float invg = 1.0f / sqrtf(kern[60]);
    auto wof = [&](int i) -> float {
        return ((unsigned)i <= 10u) ? kern[55 + i] * invg : 0.0f;
    };
    unsigned bu[4], au[4];
    #pragma unroll
    for (int jp = 0; jp < 4; ++jp) {
        const int d = 8 * lg + 2 * jp - lm - 3;    // K=32 B1 band: w[k-n-3]
        bu[jp] = pk2(wof(d), wof(d + 1));
    }
    #pragma unroll
    for (int jp = 0; jp < 2; ++jp) {
        const int e = 4 * lg + 2 * jp - lm;        // K=16 A2 band: w[k-r]
        au[jp]     = pk2(wof(e),      wof(e + 1));
        au[2 + jp] = pk2(wof(e + 16), wof(e + 17));
    }
    const f16x8 bfrag = __builtin_bit_cast(f16x8, make_uint4(bu[0], bu[1], bu[2], bu[3]));
    const f16x4 a2k0  = __builtin_bit_cast(f16x4, make_uint2(au[0], au[1]));
    const f16x4 a2k1  = __builtin_bit_cast(f16x4, make_uint2(au[2], au[3]));
    const f32x4 zero4 = {0.f, 0.f, 0.f, 0.f};

    // ---- finish staging: pack/write item 0, then items 1,2 ----
    write_item(sRaw, tid, p0a, p1a, t0a, t1a);
    #pragma unroll
    for (int j = 1; j < 3; ++j) {
        const int i = tid + NT * j;
        if (j < 2 || i < RAWR * 10) {
            float4 q0, q1, q2, q3;
            load_item(pimg, timg, ty0, tx0, interior, i, q0, q1, q2, q3);
            write_item(sRaw, i, q0, q1, q2, q3);
        }
    }
    __syncthreads();   // the only compute barrier

    // ---- per-wave: col strip ct = wv; rolling H m-tile pipeline ----
    const int co = 8 * wv;        // k-window uint base (raw px 16*wv)

    #define COMPUTE_H(mt, outf)                                                     \
    {                                                                               \
        const int rr = ((mt) == 4 && lm >= 10) ? 73 : 16 * (mt) + lm;               \
        const f16x8 aP = __builtin_bit_cast(f16x8,                                  \
            *(const uint4*)&sRaw[0][rr][co + 4 * lg]);                              \
        const f16x8 aT = __builtin_bit_cast(f16x8,                                  \
            *(const uint4*)&sRaw[1][rr][co + 4 * lg]);                              \
        f16x8 af[5];                                                                \
        af[0] = aP; af[1] = aT;                                                     \
        af[2] = aP * aP;                                                            \
        af[3] = aT * aT;                                                            \
        af[4] = aP * aT;                                                            \
        _Pragma("unroll")                                                           \
        for (int ch = 0; ch < 5; ++ch) {                                            \
            const f32x4 h = __builtin_amdgcn_mfma_f32_16x16x32_f16(af[ch], bfrag,   \
                                                                   zero4, 0, 0, 0); \
            outf[ch] = __builtin_bit_cast(f16x4,                                    \
                make_uint2(pk2(h[0], h[1]), pk2(h[2], h[3])));                      \
        }                                                                           \
    }

    f16x4 bcur[5], bnext[5];
    COMPUTE_H(0, bcur);

    float lsum = 0.f;
    #pragma unroll
    for (int rt = 0; rt < 4; ++rt) {
        COMPUTE_H(rt + 1, bnext);

        f32x4 M[5];
        #pragma unroll
        for (int ch = 0; ch < 5; ++ch) {
            const f32x4 m0 = __builtin_amdgcn_mfma_f32_16x16x16f16(a2k0, bcur[ch], zero4, 0, 0, 0);
            M[ch]          = __builtin_amdgcn_mfma_f32_16x16x16f16(a2k1, bnext[ch], m0,   0, 0, 0);
        }

        #pragma unroll
        for (int r = 0; r < 4; ++r) {
            const float mx = M[0][r], my = M[1][r];
            const float exx = M[2][r], eyy = M[3][r], exy = M[4][r];
            const float mxx = mx * mx, myy = my * my, mxy = mx * my;
            const float sx  = exx - mxx;
            const float sy  = eyy - myy;
            const float sxy = exy - mxy;
            const float num = (2.0f * mxy + 1e-4f) * (2.0f * sxy + 9e-4f);
            const float den = (mxx + myy + 1e-4f) * (sx + sy + 9e-4f);
            lsum = fmaf(num, __builtin_amdgcn_rcpf(den), lsum);
        }

        #pragma unroll
        for (int ch = 0; ch < 5; ++ch) bcur[ch] = bnext[ch];
    }
    #undef COMPUTE_H

    // ---- block reduction -> one partial per block ----
    #pragma unroll
    for (int off = 32; off > 0; off >>= 1)
        lsum += __shfl_down(lsum, off, 64);
    if (lane == 0) sRed[wv] = lsum;
    __syncthreads();
    if (tid == 0)
        partial[bid] = sRed[0] + sRed[1] + sRed[2] + sRed[3];
}

// ---------------------------------------------------------------------------
// Final reduction: sum partials, out = 1 - mean   (1 block x 1024 threads)
// ---------------------------------------------------------------------------
#define NR 1024
__global__ __launch_bounds__(NR) void ssim_reduce_kernel(
    const float* __restrict__ partial, float* __restrict__ out,
    int n, float inv_npix)
{
    __shared__ float sRed[16];
    float s = 0.0f;
    const int n4 = n >> 2;
    for (int i = threadIdx.x; i < n4; i += NR) {
        const float4 v = ((const float4*)partial)[i];
        s += (v.x + v.y) + (v.z + v.w);
    }
    for (int i = (n4 << 2) + threadIdx.x; i < n; i += NR) s += partial[i];
    #pragma unroll
    for (int off = 32; off > 0; off >>= 1)
        s += __shfl_down(s, off, 64);
    if ((threadIdx.x & 63) == 0) sRed[threadIdx.x >> 6] = s;
    __syncthreads();
    if (threadIdx.x == 0) {
        float tot = 0.0f;
        #pragma unroll
        for (int q = 0; q < 16; ++q) tot += sRed[q];
        out[0] = 1.0f - tot * inv_npix;
    }
}

extern "C" void kernel_launch(void* const* d_in, const int* in_sizes, int n_in,
                              void* d_out, int out_size, void* d_ws, size_t ws_size,
                              hipStream_t stream) {
    const float* pred   = (const float*)d_in[0];
    const float* target = (const float*)d_in[1];
    const float* kern   = (const float*)d_in[2];
    float* out     = (float*)d_out;
    float* partial = (float*)d_ws;                          // nblocks floats

    const int nimg    = in_sizes[0] / (IMG * IMG);          // 64
    const int nblocks = (IMG / BT) * (IMG / BT) * nimg;     // 4096 (mult of 8)
    const float inv_npix = 1.0f / ((float)nimg * (float)(IMG * IMG));

    ssim_mfma_kernel<<<dim3(nblocks), NT, 0, stream>>>(pred, target, kern, partial);
    ssim_reduce_kernel<<<1, NR, 0, stream>>>(partial, out, nblocks, inv_npix);
}

// Round 22
// 35.908 us; speedup vs baseline: 1.1498x; 1.1176x over previous
//
#include <hip/hip_runtime.h>

#define NT   256
#define IMG  512
#define BT   64     // block output tile: 64x64 (4 waves x 4 rt-quadrants)
#define RAWR 74     // staged rows: 64+10 halo; rows 74..79 have zero V-weight
#define RAWU 44     // raw row stride in uints (40 data + 4; odd*4 -> 2-way banks max)
#define WS_PARTIAL_OFF 1024   // floats; band table occupies first 4KB of ws

typedef _Float16 f16x8 __attribute__((ext_vector_type(8)));
typedef _Float16 f16x4 __attribute__((ext_vector_type(4)));
typedef float    f32x4 __attribute__((ext_vector_type(4)));

__device__ inline unsigned pk2(float a, float b) {
    auto r = __builtin_amdgcn_cvt_pkrtz(a, b);     // f32x2 -> f16x2 (RTZ)
    return __builtin_bit_cast(unsigned, r);
}

// ---------------------------------------------------------------------------
// One-time init: per-lane band fragments -> ws (kept separate: rounds 18/21
// showed fusing it in-block costs 2-4 us regardless of placement).
//   tab[l*16+0..3] : B1 frag, K=32 h-conv B operand, B1[k][n]=w[k-n-3]
//   tab[l*16+4..5] : A2 k-tile 0 (K=16 v-conv A), A2[r][k]=w[k-r]
//   tab[l*16+6..7] : A2 k-tile 1,                  w[k+16-r]
// ---------------------------------------------------------------------------
__global__ void ssim_init_kernel(const float* __restrict__ kern,
                                 unsigned* __restrict__ tab) {
    const int l  = threadIdx.x;        // 0..63
    const int lm = l & 15;
    const int lg = l >> 4;
    const float invg = 1.0f / sqrtf(kern[60]);
    auto wof = [&](int i) -> float {
        return ((unsigned)i <= 10u) ? kern[55 + i] * invg : 0.0f;
    };
    unsigned bu[4], au[4];
    #pragma unroll
    for (int jp = 0; jp < 4; ++jp) {
        const int d = 8 * lg + 2 * jp - lm - 3;
        bu[jp] = pk2(wof(d), wof(d + 1));
    }
    #pragma unroll
    for (int jp = 0; jp < 2; ++jp) {
        const int e = 4 * lg + 2 * jp - lm;
        au[jp]     = pk2(wof(e),      wof(e + 1));
        au[2 + jp] = pk2(wof(e + 16), wof(e + 17));
    }
    *(uint4*)&tab[l * 16]     = make_uint4(bu[0], bu[1], bu[2], bu[3]);
    *(uint4*)&tab[l * 16 + 4] = make_uint4(au[0], au[1], au[2], au[3]);
}

// ---------------------------------------------------------------------------
// SSIM via MFMA, v10 (restored round-16 best: 35.8 us).
// FINAL-FORM RATIONALE: latency-bound (no pipe >35%), and every lever family
// was A/B'd against this structure and lost:
//   v5 direct-global frags (-37%), v6 T14 2-tile preload (-33%),
//   v7 T2 XOR swizzle (-20%), v11 fused atomic reduce (-7x: agent-scope
//   atomics poison XCD L2), v12/v15 init fusion (-6/-12%), v13 setprio
//   (null), v14 64x128 wide tile (-15%).
// Compute structure (bit-exact, verified rounds 14-21):
//   H-conv:  H[m][16ct+n] = sum_k raw[m][16ct+k] * B1[k][n], B1[k][n]=w[k-n-3]
//   V-conv:  out[16rt+r][n] = sum_j w[j-r] * H[16rt+j][n] (two chained K=16
//            MFMAs; C-layout of K=32 MFMA == B-layout of K=16 MFMA)
//   PP/TT/PT A-frags derived in-register as products of P/T frags.
//   74 staged rows; mt=4 lm>=10 clamps to row 73 (zero V-weight, bit-exact).
// launch_bounds(256,4): round 4 showed tighter caps spill to scratch.
// ---------------------------------------------------------------------------
__global__ __launch_bounds__(NT, 4) void ssim_mfma_kernel(
    const float* __restrict__ pred,
    const float* __restrict__ target,
    const unsigned* __restrict__ tab,
    float* __restrict__ partial)
{
    __shared__ __align__(16) unsigned sRaw[2][RAWR][RAWU];   // 25.4 KB
    __shared__ float sRed[4];

    const int tid = threadIdx.x;

    // ---- bijective XCD swizzle (gridDim.x % 8 == 0) ----
    const int bid   = blockIdx.x;
    const int chunk = (int)gridDim.x >> 3;
    const int swz   = (bid & 7) * chunk + (bid >> 3);
    const int img   = swz >> 6;               // 64 tiles per image
    const int rem   = swz & 63;
    const int tx0   = (rem & 7) * BT;
    const int ty0   = (rem >> 3) * BT;

    const int lane = tid & 63;
    const int wv   = tid >> 6;
    const int lm   = lane & 15;     // m (A row) / n (B col) / C col
    const int lg   = lane >> 4;     // k-group; C row-group

    // ---- band fragments: two L2-hit vector loads ----
    const uint4 bq = *(const uint4*)&tab[lane * 16];
    const uint4 aq = *(const uint4*)&tab[lane * 16 + 4];
    const f16x8 bfrag = __builtin_bit_cast(f16x8, bq);
    const f16x4 a2k0  = __builtin_bit_cast(f16x4, make_uint2(aq.x, aq.y));
    const f16x4 a2k1  = __builtin_bit_cast(f16x4, make_uint2(aq.z, aq.w));
    const f32x4 zero4 = {0.f, 0.f, 0.f, 0.f};

    // ---- stage raw P,T (f16): 74 rows x 10 groups of 8 px ----
    {
        const float* pimg = pred   + (size_t)img * (IMG * IMG);
        const float* timg = target + (size_t)img * (IMG * IMG);
        if ((unsigned)(tx0 - 64) <= 320u && (unsigned)(ty0 - 64) <= 320u) {
            #pragma unroll
            for (int i = tid; i < RAWR * 10; i += NT) {
                const int r  = i / 10;
                const int cg = i - r * 10;
                const float* prow = pimg + (ty0 - 5 + r) * IMG + (tx0 - 8 + 8 * cg);
                const float* trow = timg + (ty0 - 5 + r) * IMG + (tx0 - 8 + 8 * cg);
                const float4 p0 = *(const float4*)(prow);
                const float4 p1 = *(const float4*)(prow + 4);
                const float4 t0 = *(const float4*)(trow);
                const float4 t1 = *(const float4*)(trow + 4);
                const int u = 4 * cg;
                *(uint4*)&sRaw[0][r][u] = make_uint4(pk2(p0.x, p0.y), pk2(p0.z, p0.w),
                                                     pk2(p1.x, p1.y), pk2(p1.z, p1.w));
                *(uint4*)&sRaw[1][r][u] = make_uint4(pk2(t0.x, t0.y), pk2(t0.z, t0.w),
                                                     pk2(t1.x, t1.y), pk2(t1.z, t1.w));
            }
        } else {
            for (int i = tid; i < RAWR * 10; i += NT) {
                const int r  = i / 10;
                const int cg = i - r * 10;
                const int gy = ty0 - 5 + r;
                const int gx = tx0 - 8 + 8 * cg;     // multiple of 4
                float4 p0 = make_float4(0.f, 0.f, 0.f, 0.f), p1 = p0, t0 = p0, t1 = p0;
                if ((unsigned)gy < IMG) {
                    const float* prow = pimg + gy * IMG;
                    const float* trow = timg + gy * IMG;
                    if ((unsigned)gx < IMG) {
                        p0 = *(const float4*)(prow + gx);
                        t0 = *(const float4*)(trow + gx);
                    }
                    if ((unsigned)(gx + 4) < IMG) {
                        p1 = *(const float4*)(prow + gx + 4);
                        t1 = *(const float4*)(trow + gx + 4);
                    }
                }
                const int u = 4 * cg;
                *(uint4*)&sRaw[0][r][u] = make_uint4(pk2(p0.x, p0.y), pk2(p0.z, p0.w),
                                                     pk2(p1.x, p1.y), pk2(p1.z, p1.w));
                *(uint4*)&sRaw[1][r][u] = make_uint4(pk2(t0.x, t0.y), pk2(t0.z, t0.w),
                                                     pk2(t1.x, t1.y), pk2(t1.z, t1.w));
            }
        }
    }
    __syncthreads();   // the only compute barrier

    // ---- per-wave: col strip ct = wv; rolling H m-tile pipeline ----
    const int co = 8 * wv;        // k-window uint base (raw px 16*wv)

    #define COMPUTE_H(mt, outf)                                                     \
    {                                                                               \
        const int rr = ((mt) == 4 && lm >= 10) ? 73 : 16 * (mt) + lm;               \
        const f16x8 aP = __builtin_bit_cast(f16x8,                                  \
            *(const uint4*)&sRaw[0][rr][co + 4 * lg]);                              \
        const f16x8 aT = __builtin_bit_cast(f16x8,                                  \
            *(const uint4*)&sRaw[1][rr][co + 4 * lg]);                              \
        f16x8 af[5];                                                                \
        af[0] = aP; af[1] = aT;                                                     \
        af[2] = aP * aP;                                                            \
        af[3] = aT * aT;                                                            \
        af[4] = aP * aT;                                                            \
        _Pragma("unroll")                                                           \
        for (int ch = 0; ch < 5; ++ch) {                                            \
            const f32x4 h = __builtin_amdgcn_mfma_f32_16x16x32_f16(af[ch], bfrag,   \
                                                                   zero4, 0, 0, 0); \
            outf[ch] = __builtin_bit_cast(f16x4,                                    \
                make_uint2(pk2(h[0], h[1]), pk2(h[2], h[3])));                      \
        }                                                                           \
    }

    f16x4 bcur[5], bnext[5];
    COMPUTE_H(0, bcur);

    float lsum = 0.f;
    #pragma unroll
    for (int rt = 0; rt < 4; ++rt) {
        COMPUTE_H(rt + 1, bnext);

        f32x4 M[5];
        #pragma unroll
        for (int ch = 0; ch < 5; ++ch) {
            const f32x4 m0 = __builtin_amdgcn_mfma_f32_16x16x16f16(a2k0, bcur[ch], zero4, 0, 0, 0);
            M[ch]          = __builtin_amdgcn_mfma_f32_16x16x16f16(a2k1, bnext[ch], m0,   0, 0, 0);
        }

        #pragma unroll
        for (int r = 0; r < 4; ++r) {
            const float mx = M[0][r], my = M[1][r];
            const float exx = M[2][r], eyy = M[3][r], exy = M[4][r];
            const float mxx = mx * mx, myy = my * my, mxy = mx * my;
            const float sx  = exx - mxx;
            const float sy  = eyy - myy;
            const float sxy = exy - mxy;
            const float num = (2.0f * mxy + 1e-4f) * (2.0f * sxy + 9e-4f);
            const float den = (mxx + myy + 1e-4f) * (sx + sy + 9e-4f);
            lsum = fmaf(num, __builtin_amdgcn_rcpf(den), lsum);
        }

        #pragma unroll
        for (int ch = 0; ch < 5; ++ch) bcur[ch] = bnext[ch];
    }
    #undef COMPUTE_H

    // ---- block reduction -> one partial per block ----
    #pragma unroll
    for (int off = 32; off > 0; off >>= 1)
        lsum += __shfl_down(lsum, off, 64);
    if (lane == 0) sRed[wv] = lsum;
    __syncthreads();
    if (tid == 0)
        partial[bid] = sRed[0] + sRed[1] + sRed[2] + sRed[3];
}

// ---------------------------------------------------------------------------
// Final reduction: sum partials, out = 1 - mean   (1 block x 1024 threads)
// ---------------------------------------------------------------------------
#define NR 1024
__global__ __launch_bounds__(NR) void ssim_reduce_kernel(
    const float* __restrict__ partial, float* __restrict__ out,
    int n, float inv_npix)
{
    __shared__ float sRed[16];
    float s = 0.0f;
    const int n4 = n >> 2;
    for (int i = threadIdx.x; i < n4; i += NR) {
        const float4 v = ((const float4*)partial)[i];
        s += (v.x + v.y) + (v.z + v.w);
    }
    for (int i = (n4 << 2) + threadIdx.x; i < n; i += NR) s += partial[i];
    #pragma unroll
    for (int off = 32; off > 0; off >>= 1)
        s += __shfl_down(s, off, 64);
    if ((threadIdx.x & 63) == 0) sRed[threadIdx.x >> 6] = s;
    __syncthreads();
    if (threadIdx.x == 0) {
        float tot = 0.0f;
        #pragma unroll
        for (int q = 0; q < 16; ++q) tot += sRed[q];
        out[0] = 1.0f - tot * inv_npix;
    }
}

extern "C" void kernel_launch(void* const* d_in, const int* in_sizes, int n_in,
                              void* d_out, int out_size, void* d_ws, size_t ws_size,
                              hipStream_t stream) {
    const float* pred   = (const float*)d_in[0];
    const float* target = (const float*)d_in[1];
    const float* kern   = (const float*)d_in[2];
    float* out     = (float*)d_out;
    unsigned* tab  = (unsigned*)d_ws;                       // 4 KB band table
    float* partial = (float*)d_ws + WS_PARTIAL_OFF;         // per-block sums

    const int nimg    = in_sizes[0] / (IMG * IMG);          // 64
    const int nblocks = (IMG / BT) * (IMG / BT) * nimg;     // 4096 (mult of 8)
    const float inv_npix = 1.0f / ((float)nimg * (float)(IMG * IMG));

    ssim_init_kernel<<<1, 64, 0, stream>>>(kern, tab);
    ssim_mfma_kernel<<<dim3(nblocks), NT, 0, stream>>>(pred, target, tab, partial);
    ssim_reduce_kernel<<<1, NR, 0, stream>>>(partial, out, nblocks, inv_npix);
}